// Round 5
// baseline (576.842 us; speedup 1.0000x reference)
//
#include <hip/hip_runtime.h>

#define BATCH 512
#define NI 1152
#define ND 8
#define NO 10
#define NE 16

constexpr int THREADS = 512;
constexpr int WAVES   = THREADS / 64;   // 8
constexpr int QUADS   = THREADS / 4;    // 128 i-rows per sweep
constexpr int ITEMS   = NI / QUADS;     // 9 (exact: 1152 = 128*9)
constexpr int BB      = 2;              // batch elements per block (W reuse)
constexpr int BPG     = BATCH / BB;     // 256 blocks per out-capsule

// One block per (o, 2 b's). Each thread owns ITEMS (i, e4) cells of the
// [1152 x 16] priors slice for each of the 2 b's, kept in registers/AGPRs
// (2 x 9 float4 = 72 regs). Each W[o,i,:,:] float4 load feeds 8 FMAs.
//
// Register discipline (rounds 2-4 post-mortem): the k-loop MUST be fully
// unrolled (runtime-indexed p[] would go to scratch), but full unroll lets
// the pre-RA scheduler hoist up to 72 W float4 loads -> pressure >> 128 ->
// 0.5-1 GB/call scratch spill (WRITE_SIZE 860 MB, VALUBusy 9%).
// sched_barrier(0) between iteration halves caps in-flight W loads at 4
// float4 (16 regs): peak live ~= p(72)+xa/xc(16)+v(8)+W(16)+addr < 128.
// Latency hiding comes from TLP (16 waves/CU), not load pipelining.
__global__ __launch_bounds__(THREADS, 2)
void caps_routing(const float* __restrict__ x,
                  const float* __restrict__ Wt,
                  float* __restrict__ out)
{
    const int o  = blockIdx.x / BPG;
    const int b0 = (blockIdx.x % BPG) * BB;

    __shared__ __align__(16) float red[BB][WAVES * 16];
    __shared__ float sv[BB][16];
    __shared__ float rmax[BB][WAVES];
    __shared__ float rsum[BB][WAVES];

    const int t    = threadIdx.x;
    const int lane = t & 63;
    const int w    = t >> 6;
    const int e4   = t & 3;     // which float4 of the 16-wide E dim
    const int iq   = t >> 2;    // i-quad id, i = iq + k*QUADS

    const float* xb = x  + (size_t)b0 * (NI * ND);
    const float* Wo = Wt + (size_t)o * ((size_t)NI * ND * NE);

    float4 p[BB][ITEMS];     // register-resident priors slices
    float  lg[BB][ITEMS];    // register-resident logits
    float4 acc[BB];
#pragma unroll
    for (int bb = 0; bb < BB; ++bb) acc[bb] = make_float4(0.f, 0.f, 0.f, 0.f);

    // ---- priors = x[b,i,:] @ W[o,i,:,:], fused with iter-0 uniform sum ----
#pragma unroll
    for (int k = 0; k < ITEMS; ++k) {
        const int i = iq + k * QUADS;
        float4 xa[BB], xc[BB];
#pragma unroll
        for (int bb = 0; bb < BB; ++bb) {
            const float* xr = xb + (size_t)bb * (NI * ND) + (size_t)i * ND;
            xa[bb] = *(const float4*)(xr);
            xc[bb] = *(const float4*)(xr + 4);
        }
        const float4* Wp = (const float4*)(Wo + (size_t)i * (ND * NE));
        float4 v[BB];
#pragma unroll
        for (int bb = 0; bb < BB; ++bb) v[bb] = make_float4(0.f, 0.f, 0.f, 0.f);
#define DSTEP(dd, FIELD, ARR) { const float4 wv = Wp[(dd)*4 + e4]; \
        _Pragma("unroll") \
        for (int bb = 0; bb < BB; ++bb) { const float xs = ARR[bb].FIELD; \
            v[bb].x += xs*wv.x; v[bb].y += xs*wv.y; \
            v[bb].z += xs*wv.z; v[bb].w += xs*wv.w; } }
        DSTEP(0, x, xa) DSTEP(1, y, xa) DSTEP(2, z, xa) DSTEP(3, w, xa)
        __builtin_amdgcn_sched_barrier(0);   // cap W-load pipeline depth
        DSTEP(4, x, xc) DSTEP(5, y, xc) DSTEP(6, z, xc) DSTEP(7, w, xc)
#undef DSTEP
#pragma unroll
        for (int bb = 0; bb < BB; ++bb) {
            p[bb][k] = v[bb];
            acc[bb].x += v[bb].x; acc[bb].y += v[bb].y;
            acc[bb].z += v[bb].z; acc[bb].w += v[bb].w;
        }
        __builtin_amdgcn_sched_barrier(0);   // no cross-iteration hoisting
    }

    // ---- s0 = mean_i priors : reduce across quads (same e4) ----
#pragma unroll
    for (int bb = 0; bb < BB; ++bb) {
#pragma unroll
        for (int off = 4; off <= 32; off <<= 1) {
            acc[bb].x += __shfl_xor(acc[bb].x, off);
            acc[bb].y += __shfl_xor(acc[bb].y, off);
            acc[bb].z += __shfl_xor(acc[bb].z, off);
            acc[bb].w += __shfl_xor(acc[bb].w, off);
        }
        if (lane < 4) *(float4*)&red[bb][w * 16 + e4 * 4] = acc[bb];
    }
    __syncthreads();
    if (t < 16 * BB) {
        const int bb = t >> 4, e = t & 15;
        float s = 0.f;
#pragma unroll
        for (int q = 0; q < WAVES; ++q) s += red[bb][q * 16 + e];
        sv[bb][e] = s * (1.0f / (float)NI);
    }
    __syncthreads();

    // ---- squash(s0) -> outv (each thread keeps its e4 slice, all bb) ----
    float4 outv[BB];
#pragma unroll
    for (int bb = 0; bb < BB; ++bb) {
        float sq = 0.f;
#pragma unroll
        for (int e = 0; e < 16; ++e) { const float vv = sv[bb][e]; sq += vv * vv; }
        const float scale = sqrtf(sq) / (1.0f + sq);
        outv[bb].x = sv[bb][e4 * 4 + 0] * scale;
        outv[bb].y = sv[bb][e4 * 4 + 1] * scale;
        outv[bb].z = sv[bb][e4 * 4 + 2] * scale;
        outv[bb].w = sv[bb][e4 * 4 + 3] * scale;
    }

    // ---- routing iterations 1 and 2 ----
    for (int it = 1; it < 3; ++it) {
        // pass A: logits += priors . outv ; track per-b max for softmax
#pragma unroll
        for (int bb = 0; bb < BB; ++bb) {
            float lmax = -1e30f;
#pragma unroll
            for (int k = 0; k < ITEMS; ++k) {
                const float4 v = p[bb][k];
                float part = v.x * outv[bb].x + v.y * outv[bb].y
                           + v.z * outv[bb].z + v.w * outv[bb].w;
                part += __shfl_xor(part, 1);   // quad reduce: full dot over 16 E
                part += __shfl_xor(part, 2);
                const float l = (it == 1) ? part : (lg[bb][k] + part);
                lg[bb][k] = l;
                lmax = fmaxf(lmax, l);
            }
            // lmax is quad-uniform already; reduce across the 16 quads only
#pragma unroll
            for (int off = 4; off <= 32; off <<= 1)
                lmax = fmaxf(lmax, __shfl_xor(lmax, off));
            if (lane == 0) rmax[bb][w] = lmax;
        }
        __syncthreads();
        float m[BB];
#pragma unroll
        for (int bb = 0; bb < BB; ++bb) {
            float mm = rmax[bb][0];
#pragma unroll
            for (int q = 1; q < WAVES; ++q) mm = fmaxf(mm, rmax[bb][q]);
            m[bb] = mm;
        }

        // pass B: s = sum_i softmax(lg)_i * priors_i
#pragma unroll
        for (int bb = 0; bb < BB; ++bb) {
            float4 pacc = make_float4(0.f, 0.f, 0.f, 0.f);
            float  lsum = 0.f;
#pragma unroll
            for (int k = 0; k < ITEMS; ++k) {
                const float wgt = __expf(lg[bb][k] - m[bb]);
                const float4 v = p[bb][k];
                pacc.x += wgt * v.x; pacc.y += wgt * v.y;
                pacc.z += wgt * v.z; pacc.w += wgt * v.w;
                lsum += wgt;          // quad-uniform
            }
#pragma unroll
            for (int off = 4; off <= 32; off <<= 1) {
                pacc.x += __shfl_xor(pacc.x, off);
                pacc.y += __shfl_xor(pacc.y, off);
                pacc.z += __shfl_xor(pacc.z, off);
                pacc.w += __shfl_xor(pacc.w, off);
                lsum   += __shfl_xor(lsum, off);
            }
            if (lane < 4) *(float4*)&red[bb][w * 16 + e4 * 4] = pacc;
            if (lane == 0) rsum[bb][w] = lsum;
        }
        __syncthreads();
        if (t < 16 * BB) {
            const int bb = t >> 4, e = t & 15;
            float s = 0.f;
#pragma unroll
            for (int q = 0; q < WAVES; ++q) s += red[bb][q * 16 + e];
            float L = 0.f;
#pragma unroll
            for (int q = 0; q < WAVES; ++q) L += rsum[bb][q];
            sv[bb][e] = s / L;
        }
        __syncthreads();

        if (it == 1) {
            // squash -> new outv for the next pass A
#pragma unroll
            for (int bb = 0; bb < BB; ++bb) {
                float sq = 0.f;
#pragma unroll
                for (int e = 0; e < 16; ++e) { const float vv = sv[bb][e]; sq += vv * vv; }
                const float scale = sqrtf(sq) / (1.0f + sq);
                outv[bb].x = sv[bb][e4 * 4 + 0] * scale;
                outv[bb].y = sv[bb][e4 * 4 + 1] * scale;
                outv[bb].z = sv[bb][e4 * 4 + 2] * scale;
                outv[bb].w = sv[bb][e4 * 4 + 3] * scale;
            }
        }
    }

    // ---- final squash + write out[o, b0+bb, 0, 0, :] ----
    if (t < 16 * BB) {
        const int bb = t >> 4, e = t & 15;
        float sq = 0.f;
#pragma unroll
        for (int ee = 0; ee < 16; ++ee) { const float vv = sv[bb][ee]; sq += vv * vv; }
        const float scale = sqrtf(sq) / (1.0f + sq);
        out[((size_t)o * BATCH + b0 + bb) * NE + e] = sv[bb][e] * scale;
    }
}

extern "C" void kernel_launch(void* const* d_in, const int* in_sizes, int n_in,
                              void* d_out, int out_size, void* d_ws, size_t ws_size,
                              hipStream_t stream) {
    const float* x  = (const float*)d_in[0];
    const float* Wt = (const float*)d_in[1];
    float* outp = (float*)d_out;
    caps_routing<<<dim3(NO * BPG), dim3(THREADS), 0, stream>>>(x, Wt, outp);
}

// Round 6
// 199.445 us; speedup vs baseline: 2.8922x; 2.8922x over previous
//
#include <hip/hip_runtime.h>

#define BATCH 512
#define NI 1152
#define ND 8
#define NO 10
#define NE 16

constexpr int THREADS = 512;
constexpr int WAVES   = THREADS / 64;   // 8
constexpr int QUADS   = THREADS / 4;    // 128 i-rows per sweep
constexpr int ITEMS   = NI / QUADS;     // 9 (exact: 1152 = 128*9)
constexpr int BB      = 2;              // batch elements per block (W reuse)
constexpr int BPG     = BATCH / BB;     // 256 blocks per out-capsule

// One block per (o, 2 b's). Priors [2][1152][16] live in LDS (144 KiB) --
// registers provably cannot hold them: rounds 2-5 showed the allocator pins
// this kernel at 128 VGPR and spills 0.5-1 GB/call to scratch for any
// register-resident p[BB>=2][9]. LDS budget is guaranteed; register demand
// drops to ~90 live -> no spill by construction.
//
// Bank analysis (no padding needed): row = 16 floats = 64 B. A wave's b128
// access covers 16 i-rows x 4 e4-slots; bank-quad = (4*i + e4) & 7 -> each
// of the 8 quad-clusters serves exactly 8 lanes = the structural minimum
// (1 KiB / 128 B-per-clk) -> zero avoidable conflicts.
//
// Routing uses a FUSED sweep per iteration: logits are bounded (|delta| <=
// ||prior row|| ~ 16, two iters -> |lg| <~ 40 << 88), so exp() without
// max-subtraction is safe in fp32 and softmax is shift-invariant. We
// accumulate sum(exp(l)*p) and sum(exp(l)) in ONE pass over LDS and divide
// at the end: halves priors re-reads, removes the max reduction + 2
// barriers per iteration.
__global__ __launch_bounds__(THREADS, 2)
void caps_routing(const float* __restrict__ x,
                  const float* __restrict__ Wt,
                  float* __restrict__ out)
{
    const int o  = blockIdx.x / BPG;
    const int b0 = (blockIdx.x % BPG) * BB;

    __shared__ __align__(16) float pl[BB][NI][NE];        // 147456 B
    __shared__ __align__(16) float red[BB][WAVES * 16];   // 1 KiB
    __shared__ float sv[BB][16];
    __shared__ float rsum[BB][WAVES];

    const int t    = threadIdx.x;
    const int lane = t & 63;
    const int w    = t >> 6;
    const int e4   = t & 3;     // which float4 of the 16-wide E dim
    const int iq   = t >> 2;    // i-quad id, i = iq + k*QUADS

    const float* xb = x  + (size_t)b0 * (NI * ND);
    const float* Wo = Wt + (size_t)o * ((size_t)NI * ND * NE);

    float lg[BB][ITEMS];     // logits: quad-uniform, 18 regs
    float4 acc[BB];
#pragma unroll
    for (int bb = 0; bb < BB; ++bb) acc[bb] = make_float4(0.f, 0.f, 0.f, 0.f);

    // ---- priors = x[b,i,:] @ W[o,i,:,:] -> LDS, fused iter-0 uniform sum ----
#pragma unroll
    for (int k = 0; k < ITEMS; ++k) {
        const int i = iq + k * QUADS;
        float4 xa[BB], xc[BB];
#pragma unroll
        for (int bb = 0; bb < BB; ++bb) {
            const float* xr = xb + (size_t)bb * (NI * ND) + (size_t)i * ND;
            xa[bb] = *(const float4*)(xr);
            xc[bb] = *(const float4*)(xr + 4);
        }
        const float4* Wp = (const float4*)(Wo + (size_t)i * (ND * NE));
        float4 v[BB];
#pragma unroll
        for (int bb = 0; bb < BB; ++bb) v[bb] = make_float4(0.f, 0.f, 0.f, 0.f);
#define DSTEP(dd, FIELD, ARR) { const float4 wv = Wp[(dd)*4 + e4]; \
        _Pragma("unroll") \
        for (int bb = 0; bb < BB; ++bb) { const float xs = ARR[bb].FIELD; \
            v[bb].x += xs*wv.x; v[bb].y += xs*wv.y; \
            v[bb].z += xs*wv.z; v[bb].w += xs*wv.w; } }
        DSTEP(0, x, xa) DSTEP(1, y, xa) DSTEP(2, z, xa) DSTEP(3, w, xa)
        DSTEP(4, x, xc) DSTEP(5, y, xc) DSTEP(6, z, xc) DSTEP(7, w, xc)
#undef DSTEP
#pragma unroll
        for (int bb = 0; bb < BB; ++bb) {
            *(float4*)&pl[bb][i][e4 * 4] = v[bb];
            acc[bb].x += v[bb].x; acc[bb].y += v[bb].y;
            acc[bb].z += v[bb].z; acc[bb].w += v[bb].w;
        }
    }

    // ---- s0 = mean_i priors : reduce across quads (same e4) ----
#pragma unroll
    for (int bb = 0; bb < BB; ++bb) {
#pragma unroll
        for (int off = 4; off <= 32; off <<= 1) {
            acc[bb].x += __shfl_xor(acc[bb].x, off);
            acc[bb].y += __shfl_xor(acc[bb].y, off);
            acc[bb].z += __shfl_xor(acc[bb].z, off);
            acc[bb].w += __shfl_xor(acc[bb].w, off);
        }
        if (lane < 4) *(float4*)&red[bb][w * 16 + e4 * 4] = acc[bb];
    }
    __syncthreads();
    if (t < 16 * BB) {
        const int bb = t >> 4, e = t & 15;
        float s = 0.f;
#pragma unroll
        for (int q = 0; q < WAVES; ++q) s += red[bb][q * 16 + e];
        sv[bb][e] = s * (1.0f / (float)NI);
    }
    __syncthreads();

    // ---- squash(s0) -> outv (each thread keeps its e4 slice, all bb) ----
    float4 outv[BB];
#pragma unroll
    for (int bb = 0; bb < BB; ++bb) {
        float sq = 0.f;
#pragma unroll
        for (int e = 0; e < 16; ++e) { const float vv = sv[bb][e]; sq += vv * vv; }
        const float scale = sqrtf(sq) / (1.0f + sq);
        outv[bb].x = sv[bb][e4 * 4 + 0] * scale;
        outv[bb].y = sv[bb][e4 * 4 + 1] * scale;
        outv[bb].z = sv[bb][e4 * 4 + 2] * scale;
        outv[bb].w = sv[bb][e4 * 4 + 3] * scale;
    }

    // ---- routing iterations 1 and 2: single fused sweep per iteration ----
    for (int it = 1; it < 3; ++it) {
#pragma unroll
        for (int bb = 0; bb < BB; ++bb) {
            float4 pacc = make_float4(0.f, 0.f, 0.f, 0.f);
            float  lsum = 0.f;
#pragma unroll
            for (int k = 0; k < ITEMS; ++k) {
                const int i = iq + k * QUADS;
                const float4 v = *(const float4*)&pl[bb][i][e4 * 4];
                float part = v.x * outv[bb].x + v.y * outv[bb].y
                           + v.z * outv[bb].z + v.w * outv[bb].w;
                part += __shfl_xor(part, 1);   // quad reduce: full dot over 16 E
                part += __shfl_xor(part, 2);
                const float l = (it == 1) ? part : (lg[bb][k] + part);
                lg[bb][k] = l;
                const float wgt = __expf(l);   // no max-sub: |l| <~ 40, safe
                pacc.x += wgt * v.x; pacc.y += wgt * v.y;
                pacc.z += wgt * v.z; pacc.w += wgt * v.w;
                lsum += wgt;                   // quad-uniform
            }
#pragma unroll
            for (int off = 4; off <= 32; off <<= 1) {
                pacc.x += __shfl_xor(pacc.x, off);
                pacc.y += __shfl_xor(pacc.y, off);
                pacc.z += __shfl_xor(pacc.z, off);
                pacc.w += __shfl_xor(pacc.w, off);
                lsum   += __shfl_xor(lsum, off);
            }
            if (lane < 4) *(float4*)&red[bb][w * 16 + e4 * 4] = pacc;
            if (lane == 0) rsum[bb][w] = lsum;
        }
        __syncthreads();
        if (t < 16 * BB) {
            const int bb = t >> 4, e = t & 15;
            float s = 0.f;
#pragma unroll
            for (int q = 0; q < WAVES; ++q) s += red[bb][q * 16 + e];
            float L = 0.f;
#pragma unroll
            for (int q = 0; q < WAVES; ++q) L += rsum[bb][q];
            sv[bb][e] = s / L;
        }
        __syncthreads();

        if (it == 1) {
            // squash -> new outv for the next sweep
#pragma unroll
            for (int bb = 0; bb < BB; ++bb) {
                float sq = 0.f;
#pragma unroll
                for (int e = 0; e < 16; ++e) { const float vv = sv[bb][e]; sq += vv * vv; }
                const float scale = sqrtf(sq) / (1.0f + sq);
                outv[bb].x = sv[bb][e4 * 4 + 0] * scale;
                outv[bb].y = sv[bb][e4 * 4 + 1] * scale;
                outv[bb].z = sv[bb][e4 * 4 + 2] * scale;
                outv[bb].w = sv[bb][e4 * 4 + 3] * scale;
            }
        }
    }

    // ---- final squash + write out[o, b0+bb, 0, 0, :] ----
    if (t < 16 * BB) {
        const int bb = t >> 4, e = t & 15;
        float sq = 0.f;
#pragma unroll
        for (int ee = 0; ee < 16; ++ee) { const float vv = sv[bb][ee]; sq += vv * vv; }
        const float scale = sqrtf(sq) / (1.0f + sq);
        out[((size_t)o * BATCH + b0 + bb) * NE + e] = sv[bb][e] * scale;
    }
}

extern "C" void kernel_launch(void* const* d_in, const int* in_sizes, int n_in,
                              void* d_out, int out_size, void* d_ws, size_t ws_size,
                              hipStream_t stream) {
    const float* x  = (const float*)d_in[0];
    const float* Wt = (const float*)d_in[1];
    float* outp = (float*)d_out;
    caps_routing<<<dim3(NO * BPG), dim3(THREADS), 0, stream>>>(x, Wt, outp);
}

// Round 7
// 167.457 us; speedup vs baseline: 3.4447x; 1.1910x over previous
//
#include <hip/hip_runtime.h>

#define BATCH 512
#define NI 1152
#define ND 8
#define NO 10
#define NE 16

constexpr int THREADS = 512;
constexpr int WAVES   = THREADS / 64;   // 8
constexpr int QUADS   = THREADS / 4;    // 128 i-rows per sweep
constexpr int ITEMS   = NI / QUADS;     // 9 (exact: 1152 = 128*9)
constexpr int BB      = 2;              // batch elements per block (W reuse)
constexpr int BPG     = BATCH / BB;     // 256 blocks per out-capsule

// Round-6 post-mortem: fp32 priors in LDS = 149 KB -> 1 block/CU -> 2
// waves/SIMD -> latency-bound (VALUBusy 28%, occupancy 23%, L2 at only 26%
// of ceiling). Fix: priors stored in LDS as BF16 (storage only -- all math
// stays fp32). 2 x 1152 x 16 x 2 B = 72 KiB, total ~74 KiB -> 2 blocks/CU,
// 4 waves/SIMD: doubles latency hiding. Pack = RNE (u + 0x7fff + lsb) >> 16;
// unpack = 16-bit shift (1 VALU). Expected absmax ~ few e-3 vs threshold
// 1.7e-2 (bf16 rel err 2^-9 on priors, fp32 accumulate everywhere).
//
// Registers: round 6 measured 100 VGPR live; __launch_bounds__(512,4) caps
// at 128 -> no spill. (Register-resident priors at BB>=2 are impossible:
// rounds 2-5, allocator pins 128 VGPR -> 0.5-1 GB/call scratch spill.)
//
// Fused routing sweep (validated rounds 5-6, absmax 9.8e-4): no max-sub
// (|logit| <~ 40 << 88, softmax shift-invariant); one LDS pass per iter
// accumulating sum(exp(l)*p) and sum(exp(l)).

__device__ __forceinline__ unsigned int bf16_rne(float f) {
    const unsigned int u = __builtin_bit_cast(unsigned int, f);
    return (u + 0x7fffu + ((u >> 16) & 1u)) >> 16;
}
__device__ __forceinline__ float bf_lo(unsigned int u) {
    return __builtin_bit_cast(float, u << 16);
}
__device__ __forceinline__ float bf_hi(unsigned int u) {
    return __builtin_bit_cast(float, u & 0xffff0000u);
}

__global__ __launch_bounds__(THREADS, 4)
void caps_routing(const float* __restrict__ x,
                  const float* __restrict__ Wt,
                  float* __restrict__ out)
{
    const int o  = blockIdx.x / BPG;
    const int b0 = (blockIdx.x % BPG) * BB;

    __shared__ __align__(16) unsigned int pl[BB][NI][NE / 2]; // bf16x2, 73728 B
    __shared__ __align__(16) float red[BB][WAVES * 16];       // 1 KiB
    __shared__ float sv[BB][16];
    __shared__ float rsum[BB][WAVES];

    const int t    = threadIdx.x;
    const int lane = t & 63;
    const int w    = t >> 6;
    const int e4   = t & 3;     // which float4 of the 16-wide E dim
    const int iq   = t >> 2;    // i-quad id, i = iq + k*QUADS

    const float* xb = x  + (size_t)b0 * (NI * ND);
    const float* Wo = Wt + (size_t)o * ((size_t)NI * ND * NE);

    float lg[BB][ITEMS];     // logits: quad-uniform, 18 regs
    float4 acc[BB];
#pragma unroll
    for (int bb = 0; bb < BB; ++bb) acc[bb] = make_float4(0.f, 0.f, 0.f, 0.f);

    // ---- priors = x[b,i,:] @ W[o,i,:,:] -> LDS(bf16), fused iter-0 sum ----
#pragma unroll
    for (int k = 0; k < ITEMS; ++k) {
        const int i = iq + k * QUADS;
        float4 xa[BB], xc[BB];
#pragma unroll
        for (int bb = 0; bb < BB; ++bb) {
            const float* xr = xb + (size_t)bb * (NI * ND) + (size_t)i * ND;
            xa[bb] = *(const float4*)(xr);
            xc[bb] = *(const float4*)(xr + 4);
        }
        const float4* Wp = (const float4*)(Wo + (size_t)i * (ND * NE));
        float4 v[BB];
#pragma unroll
        for (int bb = 0; bb < BB; ++bb) v[bb] = make_float4(0.f, 0.f, 0.f, 0.f);
#define DSTEP(dd, FIELD, ARR) { const float4 wv = Wp[(dd)*4 + e4]; \
        _Pragma("unroll") \
        for (int bb = 0; bb < BB; ++bb) { const float xs = ARR[bb].FIELD; \
            v[bb].x += xs*wv.x; v[bb].y += xs*wv.y; \
            v[bb].z += xs*wv.z; v[bb].w += xs*wv.w; } }
        DSTEP(0, x, xa) DSTEP(1, y, xa) DSTEP(2, z, xa) DSTEP(3, w, xa)
        DSTEP(4, x, xc) DSTEP(5, y, xc) DSTEP(6, z, xc) DSTEP(7, w, xc)
#undef DSTEP
#pragma unroll
        for (int bb = 0; bb < BB; ++bb) {
            uint2 pk;
            pk.x = bf16_rne(v[bb].x) | (bf16_rne(v[bb].y) << 16);
            pk.y = bf16_rne(v[bb].z) | (bf16_rne(v[bb].w) << 16);
            *(uint2*)&pl[bb][i][e4 * 2] = pk;
            acc[bb].x += v[bb].x; acc[bb].y += v[bb].y;
            acc[bb].z += v[bb].z; acc[bb].w += v[bb].w;
        }
    }

    // ---- s0 = mean_i priors : reduce across quads (same e4) ----
#pragma unroll
    for (int bb = 0; bb < BB; ++bb) {
#pragma unroll
        for (int off = 4; off <= 32; off <<= 1) {
            acc[bb].x += __shfl_xor(acc[bb].x, off);
            acc[bb].y += __shfl_xor(acc[bb].y, off);
            acc[bb].z += __shfl_xor(acc[bb].z, off);
            acc[bb].w += __shfl_xor(acc[bb].w, off);
        }
        if (lane < 4) *(float4*)&red[bb][w * 16 + e4 * 4] = acc[bb];
    }
    __syncthreads();
    if (t < 16 * BB) {
        const int bb = t >> 4, e = t & 15;
        float s = 0.f;
#pragma unroll
        for (int q = 0; q < WAVES; ++q) s += red[bb][q * 16 + e];
        sv[bb][e] = s * (1.0f / (float)NI);
    }
    __syncthreads();

    // ---- squash(s0) -> outv (each thread keeps its e4 slice, all bb) ----
    float4 outv[BB];
#pragma unroll
    for (int bb = 0; bb < BB; ++bb) {
        float sq = 0.f;
#pragma unroll
        for (int e = 0; e < 16; ++e) { const float vv = sv[bb][e]; sq += vv * vv; }
        const float scale = sqrtf(sq) / (1.0f + sq);
        outv[bb].x = sv[bb][e4 * 4 + 0] * scale;
        outv[bb].y = sv[bb][e4 * 4 + 1] * scale;
        outv[bb].z = sv[bb][e4 * 4 + 2] * scale;
        outv[bb].w = sv[bb][e4 * 4 + 3] * scale;
    }

    // ---- routing iterations 1 and 2: single fused sweep per iteration ----
    for (int it = 1; it < 3; ++it) {
#pragma unroll
        for (int bb = 0; bb < BB; ++bb) {
            float4 pacc = make_float4(0.f, 0.f, 0.f, 0.f);
            float  lsum = 0.f;
#pragma unroll
            for (int k = 0; k < ITEMS; ++k) {
                const int i = iq + k * QUADS;
                const uint2 pk = *(const uint2*)&pl[bb][i][e4 * 2];
                const float vx = bf_lo(pk.x), vy = bf_hi(pk.x);
                const float vz = bf_lo(pk.y), vw = bf_hi(pk.y);
                float part = vx * outv[bb].x + vy * outv[bb].y
                           + vz * outv[bb].z + vw * outv[bb].w;
                part += __shfl_xor(part, 1);   // quad reduce: full dot over 16 E
                part += __shfl_xor(part, 2);
                const float l = (it == 1) ? part : (lg[bb][k] + part);
                lg[bb][k] = l;
                const float wgt = __expf(l);   // no max-sub: |l| <~ 40, safe
                pacc.x += wgt * vx; pacc.y += wgt * vy;
                pacc.z += wgt * vz; pacc.w += wgt * vw;
                lsum += wgt;                   // quad-uniform
            }
#pragma unroll
            for (int off = 4; off <= 32; off <<= 1) {
                pacc.x += __shfl_xor(pacc.x, off);
                pacc.y += __shfl_xor(pacc.y, off);
                pacc.z += __shfl_xor(pacc.z, off);
                pacc.w += __shfl_xor(pacc.w, off);
                lsum   += __shfl_xor(lsum, off);
            }
            if (lane < 4) *(float4*)&red[bb][w * 16 + e4 * 4] = pacc;
            if (lane == 0) rsum[bb][w] = lsum;
        }
        __syncthreads();
        if (t < 16 * BB) {
            const int bb = t >> 4, e = t & 15;
            float s = 0.f;
#pragma unroll
            for (int q = 0; q < WAVES; ++q) s += red[bb][q * 16 + e];
            float L = 0.f;
#pragma unroll
            for (int q = 0; q < WAVES; ++q) L += rsum[bb][q];
            sv[bb][e] = s / L;
        }
        __syncthreads();

        if (it == 1) {
            // squash -> new outv for the next sweep
#pragma unroll
            for (int bb = 0; bb < BB; ++bb) {
                float sq = 0.f;
#pragma unroll
                for (int e = 0; e < 16; ++e) { const float vv = sv[bb][e]; sq += vv * vv; }
                const float scale = sqrtf(sq) / (1.0f + sq);
                outv[bb].x = sv[bb][e4 * 4 + 0] * scale;
                outv[bb].y = sv[bb][e4 * 4 + 1] * scale;
                outv[bb].z = sv[bb][e4 * 4 + 2] * scale;
                outv[bb].w = sv[bb][e4 * 4 + 3] * scale;
            }
        }
    }

    // ---- final squash + write out[o, b0+bb, 0, 0, :] ----
    if (t < 16 * BB) {
        const int bb = t >> 4, e = t & 15;
        float sq = 0.f;
#pragma unroll
        for (int ee = 0; ee < 16; ++ee) { const float vv = sv[bb][ee]; sq += vv * vv; }
        const float scale = sqrtf(sq) / (1.0f + sq);
        out[((size_t)o * BATCH + b0 + bb) * NE + e] = sv[bb][e] * scale;
    }
}

extern "C" void kernel_launch(void* const* d_in, const int* in_sizes, int n_in,
                              void* d_out, int out_size, void* d_ws, size_t ws_size,
                              hipStream_t stream) {
    const float* x  = (const float*)d_in[0];
    const float* Wt = (const float*)d_in[1];
    float* outp = (float*)d_out;
    caps_routing<<<dim3(NO * BPG), dim3(THREADS), 0, stream>>>(x, Wt, outp);
}